// Round 1
// baseline (1495.218 us; speedup 1.0000x reference)
//
#include <hip/hip_runtime.h>
#include <hip/hip_bf16.h>
#include <math.h>

// Problem constants
#define B_    16
#define HID   64
#define CIN   32
#define OC1   192   // 3*HID
#define CCC   16    // 2*CONNECTION
#define HW_   128
#define NPIX  (HW_*HW_)

// ---- sortable-uint encoding for float atomicMin/Max ----
__device__ __forceinline__ unsigned fenc(float f) {
    unsigned b = __float_as_uint(f);
    return (b & 0x80000000u) ? ~b : (b | 0x80000000u);
}
__device__ __forceinline__ float fdec(unsigned u) {
    unsigned b = (u & 0x80000000u) ? (u ^ 0x80000000u) : ~u;
    return __uint_as_float(b);
}

// ---------------------------------------------------------------------------
// K0: repack weights for uniform (scalar-load-friendly) access + init minmax
//  win_rp [k=ic*9+ky*3+kx][oc]          : 288 x 192
//  wsub_rp[k=ic*25+ky*5+kx][oc]         : 2400 x 16
//  wp3    [c_all=i*64+c][o]             : 256 x 192
//  bsum   [o] = sum_i b_proj[i][o]      : 192
// ---------------------------------------------------------------------------
__global__ __launch_bounds__(256) void repack_kernel(
    const float* __restrict__ w_in, const float* __restrict__ w_sub,
    const float* __restrict__ w_proj, const float* __restrict__ b_proj,
    float* __restrict__ win_rp, float* __restrict__ wsub_rp,
    float* __restrict__ wp3, float* __restrict__ bsum,
    unsigned* __restrict__ minmax)
{
    int idx = blockIdx.x * 256 + threadIdx.x;
    if (idx < 55296) {                       // w_in (192,32,3,3) -> [k][oc]
        int k = idx / 192, oc = idx - k * 192;
        win_rp[idx] = w_in[oc * 288 + k];
    } else if (idx < 55296 + 38400) {        // w_sub (16,96,5,5) -> [k][oc]
        int j = idx - 55296;
        int k = j / 16, oc = j - k * 16;
        wsub_rp[j] = w_sub[oc * 2400 + k];
    } else if (idx < 55296 + 38400 + 49152) {// w_proj (4,192,64) -> [i*64+c][o]
        int j = idx - (55296 + 38400);
        int call = j / 192, o = j - call * 192;
        int i = call >> 6, c = call & 63;
        wp3[j] = w_proj[(i * 192 + o) * 64 + c];
    } else if (idx < 55296 + 38400 + 49152 + 192) {
        int o = idx - (55296 + 38400 + 49152);
        bsum[o] = b_proj[o] + b_proj[192 + o] + b_proj[384 + o] + b_proj[576 + o];
    }
    if (idx == 0) { minmax[0] = 0xFFFFFFFFu; minmax[1] = 0u; }
}

// ---------------------------------------------------------------------------
// K1: 5x5 conv (pad 2) of concat(x, h_prev) (96ch) -> cc (16ch, fp32)
//     + fused global min/max reduction over ALL cc values
// ---------------------------------------------------------------------------
__global__ __launch_bounds__(256) void conv_sub_kernel(
    const float* __restrict__ x, const float* __restrict__ hp,
    const float* __restrict__ wsub_rp, const float* __restrict__ b_sub,
    float* __restrict__ cc, unsigned* __restrict__ minmax)
{
    __shared__ float tile[24][20][20];   // 38400 B
    __shared__ unsigned smn, smx;
    int tid = threadIdx.x;
    int b = blockIdx.z;
    int y0 = blockIdx.y * 16, x0 = blockIdx.x * 16;

    float acc[16];
#pragma unroll
    for (int j = 0; j < 16; ++j) acc[j] = b_sub[j];
    if (tid == 0) { smn = 0xFFFFFFFFu; smx = 0u; }

    for (int ch = 0; ch < 4; ++ch) {     // 4 chunks of 24 input channels
        __syncthreads();
        for (int idx = tid; idx < 24 * 400; idx += 256) {
            int icl = idx / 400; int r = idx - icl * 400;
            int yy = r / 20, xx = r - (r / 20) * 20;
            int gy = y0 + yy - 2, gx = x0 + xx - 2;
            int icg = ch * 24 + icl;
            float v = 0.f;
            if ((unsigned)gy < 128u && (unsigned)gx < 128u)
                v = (icg < 32) ? x[((b * CIN + icg) * HW_ + gy) * HW_ + gx]
                               : hp[((b * HID + (icg - 32)) * HW_ + gy) * HW_ + gx];
            tile[icl][yy][xx] = v;
        }
        __syncthreads();
        int tx = tid & 15, ty = tid >> 4;
        for (int icl = 0; icl < 24; ++icl) {
#pragma unroll
            for (int ky = 0; ky < 5; ++ky) {
#pragma unroll
                for (int kx = 0; kx < 5; ++kx) {
                    float v = tile[icl][ty + ky][tx + kx];
                    const float* wr = &wsub_rp[((ch * 24 + icl) * 25 + ky * 5 + kx) * 16];
#pragma unroll
                    for (int j = 0; j < 16; ++j) acc[j] = fmaf(v, wr[j], acc[j]);
                }
            }
        }
    }
    int tx = tid & 15, ty = tid >> 4;
    int yg = y0 + ty, xg = x0 + tx;
    float mn = acc[0], mx = acc[0];
#pragma unroll
    for (int j = 0; j < 16; ++j) {
        cc[((b * CCC + j) * HW_ + yg) * HW_ + xg] = acc[j];
        mn = fminf(mn, acc[j]); mx = fmaxf(mx, acc[j]);
    }
    atomicMin(&smn, fenc(mn));
    atomicMax(&smx, fenc(mx));
    __syncthreads();
    if (tid == 0) { atomicMin(&minmax[0], smn); atomicMax(&minmax[1], smx); }
}

// ---------------------------------------------------------------------------
// K2: 3x3 conv (pad 1) x (32ch) -> input_conv (192ch), stored bf16 in ws
// ---------------------------------------------------------------------------
__global__ __launch_bounds__(256) void conv_in_kernel(
    const float* __restrict__ x, const float* __restrict__ win_rp,
    const float* __restrict__ b_in, __hip_bfloat16* __restrict__ icbuf)
{
    __shared__ float tile[32][18][18];   // 41472 B
    int tid = threadIdx.x;
    int b = blockIdx.z;
    int y0 = blockIdx.y * 16, x0 = blockIdx.x * 16;

    for (int idx = tid; idx < 32 * 324; idx += 256) {
        int ic = idx / 324; int r = idx - ic * 324;
        int yy = r / 18, xx = r - (r / 18) * 18;
        int gy = y0 + yy - 1, gx = x0 + xx - 1;
        float v = 0.f;
        if ((unsigned)gy < 128u && (unsigned)gx < 128u)
            v = x[((b * CIN + ic) * HW_ + gy) * HW_ + gx];
        tile[ic][yy][xx] = v;
    }
    __syncthreads();

    int tx = tid & 15, ty = tid >> 4;
    int yg = y0 + ty, xg = x0 + tx;
    for (int oc0 = 0; oc0 < 192; oc0 += 16) {
        float acc[16];
#pragma unroll
        for (int j = 0; j < 16; ++j) acc[j] = b_in[oc0 + j];
        for (int ic = 0; ic < 32; ++ic) {
#pragma unroll
            for (int ky = 0; ky < 3; ++ky) {
#pragma unroll
                for (int kx = 0; kx < 3; ++kx) {
                    float v = tile[ic][ty + ky][tx + kx];
                    const float* wr = &win_rp[(ic * 9 + ky * 3 + kx) * 192 + oc0];
#pragma unroll
                    for (int j = 0; j < 16; ++j) acc[j] = fmaf(v, wr[j], acc[j]);
                }
            }
        }
#pragma unroll
        for (int j = 0; j < 16; ++j)
            icbuf[(size_t)((b * OC1 + oc0 + j) * NPIX) + yg * HW_ + xg] =
                __float2bfloat16(acc[j]);
    }
}

// ---------------------------------------------------------------------------
// K3: fused grid_sample(4 warps) + 192x256 projection + GRU gates -> h_next
//   block = 256 thr handles 64 consecutive pixels of one row (b, y, xhalf)
//   stage A: wave i computes warp-i bilinear samples -> LDS warped[c][p] bf16
//   stage B: wave w computes outputs o in {d, 64+d, 128+d : d in [16w,16w+16)}
// ---------------------------------------------------------------------------
__global__ __launch_bounds__(256) void warp_gru_kernel(
    const float* __restrict__ hp, const float* __restrict__ cc,
    const float* __restrict__ wp3, const float* __restrict__ bsum,
    const __hip_bfloat16* __restrict__ icbuf, const unsigned* __restrict__ minmax,
    float* __restrict__ out)
{
    __shared__ __hip_bfloat16 warped[256 * 64];  // [c_all][p], 32 KB
    int t = threadIdx.x;
    int b = blockIdx.z, y = blockIdx.y, xh = blockIdx.x;
    int p = t & 63;
    int xg = xh * 64 + p;

    float mn = fdec(minmax[0]), mx = fdec(minmax[1]);
    float scale = 2.0f / (mx - mn);

    // ---- stage A: bilinear gather ----
    int i = t >> 6;
    int ccbase = ((b * CCC + 2 * i) * HW_ + y) * HW_ + xg;
    float gxn = (cc[ccbase] - mn) * scale - 1.0f;          // grid[...,0] = x
    float gyn = (cc[ccbase + NPIX] - mn) * scale - 1.0f;   // grid[...,1] = y
    float gx = (gxn + 1.0f) * 64.0f - 0.5f;                // W*0.5 = 64
    float gy = (gyn + 1.0f) * 64.0f - 0.5f;
    float x0f = floorf(gx), y0f = floorf(gy);
    float wx1 = gx - x0f, wy1 = gy - y0f;
    float wx0 = 1.0f - wx1, wy0 = 1.0f - wy1;
    int ix0 = (int)x0f, iy0 = (int)y0f;
    int ix1 = ix0 + 1, iy1 = iy0 + 1;
    bool vx0 = (unsigned)ix0 < 128u, vx1 = (unsigned)ix1 < 128u;
    bool vy0 = (unsigned)iy0 < 128u, vy1 = (unsigned)iy1 < 128u;
    float a00 = (vx0 && vy0) ? wy0 * wx0 : 0.f;
    float a01 = (vx1 && vy0) ? wy0 * wx1 : 0.f;
    float a10 = (vx0 && vy1) ? wy1 * wx0 : 0.f;
    float a11 = (vx1 && vy1) ? wy1 * wx1 : 0.f;
    int cx0 = min(max(ix0, 0), 127), cx1 = min(max(ix1, 0), 127);
    int cy0 = min(max(iy0, 0), 127), cy1 = min(max(iy1, 0), 127);
    const float* hb = hp + (size_t)b * HID * NPIX;
    int o00 = cy0 * HW_ + cx0, o01 = cy0 * HW_ + cx1;
    int o10 = cy1 * HW_ + cx0, o11 = cy1 * HW_ + cx1;
#pragma unroll 4
    for (int c = 0; c < 64; ++c) {
        const float* hc = hb + c * NPIX;
        float v = a00 * hc[o00] + a01 * hc[o01] + a10 * hc[o10] + a11 * hc[o11];
        warped[(i * 64 + c) * 64 + p] = __float2bfloat16(v);
    }
    __syncthreads();

    // ---- stage B: matvec (48 rows per wave) + gates ----
    int w = __builtin_amdgcn_readfirstlane(t >> 6);  // force SGPR -> s_loads
    int d0 = w * 16;
    float az[16], ar[16], ah[16];
#pragma unroll
    for (int j = 0; j < 16; ++j) {
        az[j] = bsum[d0 + j];
        ar[j] = bsum[64 + d0 + j];
        ah[j] = bsum[128 + d0 + j];
    }
    for (int c = 0; c < 256; ++c) {
        float v = __bfloat162float(warped[c * 64 + p]);
        const float* wr = &wp3[c * 192 + d0];
#pragma unroll
        for (int j = 0; j < 16; ++j) {
            az[j] = fmaf(v, wr[j], az[j]);
            ar[j] = fmaf(v, wr[64 + j], ar[j]);
            ah[j] = fmaf(v, wr[128 + j], ah[j]);
        }
    }
    const __hip_bfloat16* icb = icbuf + (size_t)b * OC1 * NPIX;
    int pix = y * HW_ + xg;
#pragma unroll
    for (int j = 0; j < 16; ++j) {
        int d = d0 + j;
        float xz  = __bfloat162float(icb[(size_t)d * NPIX + pix]);
        float xr  = __bfloat162float(icb[(size_t)(64 + d) * NPIX + pix]);
        float xhv = __bfloat162float(icb[(size_t)(128 + d) * NPIX + pix]);
        float hpv = hb[(size_t)d * NPIX + pix];
        float z = 1.0f / (1.0f + expf(-(xz + az[j])));
        float r = 1.0f / (1.0f + expf(-(xr + ar[j])));
        float hc = xhv + r * ah[j];
        hc = hc > 0.f ? hc : 0.2f * hc;
        out[(size_t)(b * HID + d) * NPIX + pix] = (1.f - z) * hc + z * hpv;
    }
}

// ---------------------------------------------------------------------------
extern "C" void kernel_launch(void* const* d_in, const int* in_sizes, int n_in,
                              void* d_out, int out_size, void* d_ws, size_t ws_size,
                              hipStream_t stream)
{
    const float* x      = (const float*)d_in[0];
    const float* hp     = (const float*)d_in[1];
    const float* w_in   = (const float*)d_in[2];
    const float* b_in   = (const float*)d_in[3];
    const float* w_proj = (const float*)d_in[4];
    const float* b_proj = (const float*)d_in[5];
    const float* w_sub  = (const float*)d_in[6];
    const float* b_sub  = (const float*)d_in[7];
    float* out = (float*)d_out;

    // ws layout (bytes), all 256-aligned; total ~112.6 MB
    char* ws = (char*)d_ws;
    __hip_bfloat16* icbuf = (__hip_bfloat16*)ws;            // 100,663,296
    float*    ccbuf   = (float*)(ws + 100663296);           //  16,777,216
    unsigned* minmax  = (unsigned*)(ws + 117440512);        //        256
    float*    win_rp  = (float*)(ws + 117440768);           //     221,184
    float*    wsub_rp = (float*)(ws + 117661952);           //     153,600
    float*    wp3     = (float*)(ws + 117815552);           //     196,608
    float*    bsum    = (float*)(ws + 118012160);           //       1,024

    repack_kernel<<<dim3(559), dim3(256), 0, stream>>>(
        w_in, w_sub, w_proj, b_proj, win_rp, wsub_rp, wp3, bsum, minmax);
    conv_sub_kernel<<<dim3(8, 8, B_), dim3(256), 0, stream>>>(
        x, hp, wsub_rp, b_sub, ccbuf, minmax);
    conv_in_kernel<<<dim3(8, 8, B_), dim3(256), 0, stream>>>(
        x, win_rp, b_in, icbuf);
    warp_gru_kernel<<<dim3(2, HW_, B_), dim3(256), 0, stream>>>(
        hp, ccbuf, wp3, bsum, icbuf, minmax, out);
}

// Round 2
// 925.286 us; speedup vs baseline: 1.6160x; 1.6160x over previous
//
#include <hip/hip_runtime.h>
#include <hip/hip_bf16.h>
#include <math.h>

// Problem constants
#define B_    16
#define HID   64
#define CIN   32
#define OC1   192   // 3*HID
#define CCC   16    // 2*CONNECTION
#define HW_   128
#define NPIX  (HW_*HW_)

typedef short short8 __attribute__((ext_vector_type(8)));   // 8 bf16 (4 VGPRs)
typedef float floatx4 __attribute__((ext_vector_type(4)));  // MFMA C/D

// ---- sortable-uint encoding for float atomicMin/Max ----
__device__ __forceinline__ unsigned fenc(float f) {
    unsigned b = __float_as_uint(f);
    return (b & 0x80000000u) ? ~b : (b | 0x80000000u);
}
__device__ __forceinline__ float fdec(unsigned u) {
    unsigned b = (u & 0x80000000u) ? (u ^ 0x80000000u) : ~u;
    return __uint_as_float(b);
}

// ---------------------------------------------------------------------------
// K0: repack weights + init minmax
//  wsub_rp [k=ic*25+ky*5+kx][oc]  : 2400 x 16 fp32 (conv_sub, unchanged)
//  bsum    [o] = sum_i b_proj[i][o] : 192 fp32
//  win_frag[s][mt][lane][j] bf16  : A-frags for conv_in  (9*12*64*8)
//     oc = mt*16 + (lane&15), ic = (lane>>4)*8 + j, s = ky*3+kx
//  wp_frag [kt][mt][lane][j] bf16 : A-frags for warp proj (8*12*64*8)
//     o = mt*16 + (lane&15), c_all = kt*32 + (lane>>4)*8 + j
// ---------------------------------------------------------------------------
__global__ __launch_bounds__(256) void repack_kernel(
    const float* __restrict__ w_in, const float* __restrict__ w_sub,
    const float* __restrict__ w_proj, const float* __restrict__ b_proj,
    float* __restrict__ wsub_rp, float* __restrict__ bsum,
    __hip_bfloat16* __restrict__ win_frag, __hip_bfloat16* __restrict__ wp_frag,
    unsigned* __restrict__ minmax)
{
    int idx = blockIdx.x * 256 + threadIdx.x;
    if (idx < 38400) {                       // w_sub (16,96,5,5) -> [k][oc]
        int k = idx / 16, oc = idx - k * 16;
        wsub_rp[idx] = w_sub[oc * 2400 + k];
    } else if (idx < 38400 + 192) {
        int o = idx - 38400;
        bsum[o] = b_proj[o] + b_proj[192 + o] + b_proj[384 + o] + b_proj[576 + o];
    } else if (idx < 38400 + 192 + 55296) {  // win_frag
        int j2 = idx - 38592;
        int s = j2 / 6144, r = j2 - s * 6144;
        int mt = r / 512, r2 = r - mt * 512;
        int l = r2 >> 3, j = r2 & 7;
        int oc = mt * 16 + (l & 15);
        int ic = (l >> 4) * 8 + j;
        win_frag[j2] = __float2bfloat16(w_in[oc * 288 + ic * 9 + s]);
    } else if (idx < 38400 + 192 + 55296 + 49152) { // wp_frag
        int j3 = idx - (38592 + 55296);
        int kt = j3 / 6144, r = j3 - kt * 6144;
        int mt = r / 512, r2 = r - mt * 512;
        int l = r2 >> 3, j = r2 & 7;
        int o = mt * 16 + (l & 15);
        int c_all = kt * 32 + (l >> 4) * 8 + j;
        int i = c_all >> 6, c = c_all & 63;
        wp_frag[j3] = __float2bfloat16(w_proj[(i * 192 + o) * 64 + c]);
    }
    if (idx == 0) { minmax[0] = 0xFFFFFFFFu; minmax[1] = 0u; }
}

// ---------------------------------------------------------------------------
// K0b: transpose x to channels-last bf16: xcl[b][y][x][ic]
// ---------------------------------------------------------------------------
__global__ __launch_bounds__(256) void transpose_x_kernel(
    const float* __restrict__ x, __hip_bfloat16* __restrict__ xcl)
{
    __shared__ float lds[32 * 129];
    int tid = threadIdx.x;
    int y = blockIdx.x, b = blockIdx.y;
    const float* xb = x + (size_t)b * CIN * NPIX + y * HW_;
#pragma unroll
    for (int it = 0; it < 16; ++it) {
        int idx = tid + it * 256;
        int ic = idx >> 7, xx = idx & 127;
        lds[ic * 129 + xx] = xb[(size_t)ic * NPIX + xx];
    }
    __syncthreads();
    __hip_bfloat16* o = xcl + (size_t)((b * HW_ + y) * HW_) * 32;
#pragma unroll
    for (int it = 0; it < 16; ++it) {
        int e = tid + it * 256;
        int ic = e & 31, xx = e >> 5;
        o[e] = __float2bfloat16(lds[ic * 129 + xx]);
    }
}

// ---------------------------------------------------------------------------
// K1: conv_in as MFMA implicit GEMM.
//   Block: 16x8 px tile (x-extent 16, y-extent 8), 4 waves.
//   C[192 oc][128 px] = sum over 9 shifts of W_s[192x32] * X_s[32x128].
//   Wave w owns m-tiles {3w,3w+1,3w+2}, all 8 n-tiles (n-tile = one px row).
// ---------------------------------------------------------------------------
__global__ __launch_bounds__(256) void conv_in_mfma(
    const __hip_bfloat16* __restrict__ xcl,
    const __hip_bfloat16* __restrict__ win_frag,
    const float* __restrict__ b_in, __hip_bfloat16* __restrict__ icbuf)
{
    __shared__ __align__(16) __hip_bfloat16 xt[10 * 18 * 32];  // 11520 B
    int tid = threadIdx.x;
    int w = tid >> 6, l = tid & 63;
    int quad = l >> 4, ln = l & 15;
    int b = blockIdx.z;
    int y0 = blockIdx.y * 8, x0 = blockIdx.x * 16;

    // stage halo tile [yy 0..9][xx 0..17][ic 0..31] bf16
    for (int idx = tid; idx < 720; idx += 256) {
        int pos = idx >> 2, ch = idx & 3;
        int yy = pos / 18, xx = pos - yy * 18;
        int gy = y0 + yy - 1, gx = x0 + xx - 1;
        uint4 v = make_uint4(0, 0, 0, 0);
        if ((unsigned)gy < 128u && (unsigned)gx < 128u)
            v = ((const uint4*)(xcl + (size_t)((b * HW_ + gy) * HW_ + gx) * 32))[ch];
        ((uint4*)(xt + pos * 32))[ch] = v;
    }
    __syncthreads();

    floatx4 acc[3][8];
#pragma unroll
    for (int a = 0; a < 3; ++a) {
        int ocb = (3 * w + a) * 16 + quad * 4;
        floatx4 init;
        init[0] = b_in[ocb]; init[1] = b_in[ocb + 1];
        init[2] = b_in[ocb + 2]; init[3] = b_in[ocb + 3];
#pragma unroll
        for (int nt = 0; nt < 8; ++nt) acc[a][nt] = init;
    }

#pragma unroll
    for (int s = 0; s < 9; ++s) {
        int ky = s / 3, kx = s - ky * 3;
        short8 af[3];
#pragma unroll
        for (int a = 0; a < 3; ++a)
            af[a] = *(const short8*)(win_frag + (size_t)((s * 12 + (3 * w + a)) * 64 + l) * 8);
#pragma unroll
        for (int nt = 0; nt < 8; ++nt) {
            int pos = (nt + ky) * 18 + (ln + kx);
            short8 bf = *(const short8*)(xt + pos * 32 + quad * 8);
#pragma unroll
            for (int a = 0; a < 3; ++a)
                acc[a][nt] = __builtin_amdgcn_mfma_f32_16x16x32_bf16(af[a], bf, acc[a][nt], 0, 0, 0);
        }
    }

    // store: D col = ln -> px, row = quad*4+reg -> oc within m-tile
#pragma unroll
    for (int a = 0; a < 3; ++a) {
#pragma unroll
        for (int nt = 0; nt < 8; ++nt) {
#pragma unroll
            for (int r = 0; r < 4; ++r) {
                int oc = (3 * w + a) * 16 + quad * 4 + r;
                icbuf[(size_t)(b * OC1 + oc) * NPIX + (y0 + nt) * HW_ + x0 + ln] =
                    __float2bfloat16(acc[a][nt][r]);
            }
        }
    }
}

// ---------------------------------------------------------------------------
// K2: 5x5 conv (pad 2) of concat(x, h_prev) (96ch) -> cc (16ch, fp32)
//     + fused global min/max reduction  (unchanged from R1)
// ---------------------------------------------------------------------------
__global__ __launch_bounds__(256) void conv_sub_kernel(
    const float* __restrict__ x, const float* __restrict__ hp,
    const float* __restrict__ wsub_rp, const float* __restrict__ b_sub,
    float* __restrict__ cc, unsigned* __restrict__ minmax)
{
    __shared__ float tile[24][20][20];
    __shared__ unsigned smn, smx;
    int tid = threadIdx.x;
    int b = blockIdx.z;
    int y0 = blockIdx.y * 16, x0 = blockIdx.x * 16;

    float acc[16];
#pragma unroll
    for (int j = 0; j < 16; ++j) acc[j] = b_sub[j];
    if (tid == 0) { smn = 0xFFFFFFFFu; smx = 0u; }

    for (int ch = 0; ch < 4; ++ch) {
        __syncthreads();
        for (int idx = tid; idx < 24 * 400; idx += 256) {
            int icl = idx / 400; int r = idx - icl * 400;
            int yy = r / 20, xx = r - (r / 20) * 20;
            int gy = y0 + yy - 2, gx = x0 + xx - 2;
            int icg = ch * 24 + icl;
            float v = 0.f;
            if ((unsigned)gy < 128u && (unsigned)gx < 128u)
                v = (icg < 32) ? x[((b * CIN + icg) * HW_ + gy) * HW_ + gx]
                               : hp[((b * HID + (icg - 32)) * HW_ + gy) * HW_ + gx];
            tile[icl][yy][xx] = v;
        }
        __syncthreads();
        int tx = tid & 15, ty = tid >> 4;
        for (int icl = 0; icl < 24; ++icl) {
#pragma unroll
            for (int ky = 0; ky < 5; ++ky) {
#pragma unroll
                for (int kx = 0; kx < 5; ++kx) {
                    float v = tile[icl][ty + ky][tx + kx];
                    const float* wr = &wsub_rp[((ch * 24 + icl) * 25 + ky * 5 + kx) * 16];
#pragma unroll
                    for (int j = 0; j < 16; ++j) acc[j] = fmaf(v, wr[j], acc[j]);
                }
            }
        }
    }
    int tx = tid & 15, ty = tid >> 4;
    int yg = y0 + ty, xg = x0 + tx;
    float mn = acc[0], mx = acc[0];
#pragma unroll
    for (int j = 0; j < 16; ++j) {
        cc[((b * CCC + j) * HW_ + yg) * HW_ + xg] = acc[j];
        mn = fminf(mn, acc[j]); mx = fmaxf(mx, acc[j]);
    }
    atomicMin(&smn, fenc(mn));
    atomicMax(&smx, fenc(mx));
    __syncthreads();
    if (tid == 0) { atomicMin(&minmax[0], smn); atomicMax(&minmax[1], smx); }
}

// ---------------------------------------------------------------------------
// K3: fused grid_sample(4 warps) + MFMA projection + GRU gates -> h_next
//   Block = 256 thr, 64 px (b, y, xhalf).
//   Stage A: wave i gathers warp-i bilinear samples of h_prev into LDS
//            warped[px][c_all] bf16 with 8-elem XOR swizzle (bank-uniform).
//   Stage B: C[192][64] = Wp[192x256] * warped via MFMA; wave w owns m-tiles
//            {w, w+4, w+8} (z/r/h triplet for d in [16w,16w+16)); gates fused.
// ---------------------------------------------------------------------------
__global__ __launch_bounds__(256) void warp_gru_kernel(
    const float* __restrict__ hp, const float* __restrict__ cc,
    const __hip_bfloat16* __restrict__ wp_frag, const float* __restrict__ bsum,
    const __hip_bfloat16* __restrict__ icbuf, const unsigned* __restrict__ minmax,
    float* __restrict__ out)
{
    __shared__ __align__(16) __hip_bfloat16 warped[64 * 256];  // [px][c swizzled], 32 KB
    int tid = threadIdx.x;
    int i = tid >> 6;          // wave = warp index in stage A
    int p = tid & 63;          // pixel within block
    int b = blockIdx.z, y = blockIdx.y, xh = blockIdx.x;
    int xg = xh * 64 + p;

    float mn = fdec(minmax[0]), mx = fdec(minmax[1]);
    float scale = 2.0f / (mx - mn);

    // ---- stage A: bilinear gather -> warped[p][i*64 + c] ----
    int ccbase = ((b * CCC + 2 * i) * HW_ + y) * HW_ + xg;
    float gxn = (cc[ccbase] - mn) * scale - 1.0f;
    float gyn = (cc[ccbase + NPIX] - mn) * scale - 1.0f;
    float gx = (gxn + 1.0f) * 64.0f - 0.5f;
    float gy = (gyn + 1.0f) * 64.0f - 0.5f;
    float x0f = floorf(gx), y0f = floorf(gy);
    float wx1 = gx - x0f, wy1 = gy - y0f;
    float wx0 = 1.0f - wx1, wy0 = 1.0f - wy1;
    int ix0 = (int)x0f, iy0 = (int)y0f;
    int ix1 = ix0 + 1, iy1 = iy0 + 1;
    bool vx0 = (unsigned)ix0 < 128u, vx1 = (unsigned)ix1 < 128u;
    bool vy0 = (unsigned)iy0 < 128u, vy1 = (unsigned)iy1 < 128u;
    float a00 = (vx0 && vy0) ? wy0 * wx0 : 0.f;
    float a01 = (vx1 && vy0) ? wy0 * wx1 : 0.f;
    float a10 = (vx0 && vy1) ? wy1 * wx0 : 0.f;
    float a11 = (vx1 && vy1) ? wy1 * wx1 : 0.f;
    int cx0 = min(max(ix0, 0), 127), cx1 = min(max(ix1, 0), 127);
    int cy0 = min(max(iy0, 0), 127), cy1 = min(max(iy1, 0), 127);
    const float* hb = hp + (size_t)b * HID * NPIX;
    int o00 = cy0 * HW_ + cx0, o01 = cy0 * HW_ + cx1;
    int o10 = cy1 * HW_ + cx0, o11 = cy1 * HW_ + cx1;

#pragma unroll
    for (int t = 0; t < 8; ++t) {
        short8 pk;
#pragma unroll
        for (int e = 0; e < 8; ++e) {
            const float* hc = hb + (size_t)(t * 8 + e) * NPIX;
            float v = a00 * hc[o00] + a01 * hc[o01] + a10 * hc[o10] + a11 * hc[o11];
            __hip_bfloat16 bv = __float2bfloat16(v);
            pk[e] = *reinterpret_cast<short*>(&bv);
        }
        int cs = (i * 8 + t) ^ (p & 7);
        *(short8*)(warped + p * 256 + cs * 8) = pk;
    }
    __syncthreads();

    // ---- stage B: MFMA projection + gates ----
    int w = i;                 // wave index for stage B
    int l = p;                 // lane
    int quad = l >> 4, ln = l & 15;

    floatx4 acc[3][4];
#pragma unroll
    for (int t = 0; t < 3; ++t) {
        int ob = t * 64 + 16 * w + quad * 4;
        floatx4 init;
        init[0] = bsum[ob]; init[1] = bsum[ob + 1];
        init[2] = bsum[ob + 2]; init[3] = bsum[ob + 3];
#pragma unroll
        for (int nt = 0; nt < 4; ++nt) acc[t][nt] = init;
    }

#pragma unroll
    for (int kt = 0; kt < 8; ++kt) {
        short8 af[3];
#pragma unroll
        for (int t = 0; t < 3; ++t)
            af[t] = *(const short8*)(wp_frag + (size_t)((kt * 12 + (t * 4 + w)) * 64 + l) * 8);
#pragma unroll
        for (int nt = 0; nt < 4; ++nt) {
            int pxi = nt * 16 + ln;
            int cs = (kt * 4 + quad) ^ (pxi & 7);
            short8 bf = *(const short8*)(warped + pxi * 256 + cs * 8);
#pragma unroll
            for (int t = 0; t < 3; ++t)
                acc[t][nt] = __builtin_amdgcn_mfma_f32_16x16x32_bf16(af[t], bf, acc[t][nt], 0, 0, 0);
        }
    }

    const __hip_bfloat16* icb = icbuf + (size_t)b * OC1 * NPIX;
#pragma unroll
    for (int nt = 0; nt < 4; ++nt) {
#pragma unroll
        for (int r = 0; r < 4; ++r) {
            int d = 16 * w + quad * 4 + r;
            int pxi = nt * 16 + ln;
            int pix = y * HW_ + xh * 64 + pxi;
            float xz  = __bfloat162float(icb[(size_t)d * NPIX + pix]);
            float xr  = __bfloat162float(icb[(size_t)(64 + d) * NPIX + pix]);
            float xhv = __bfloat162float(icb[(size_t)(128 + d) * NPIX + pix]);
            float hpv = hb[(size_t)d * NPIX + pix];
            float z  = 1.0f / (1.0f + expf(-(xz + acc[0][nt][r])));
            float rg = 1.0f / (1.0f + expf(-(xr + acc[1][nt][r])));
            float hc = xhv + rg * acc[2][nt][r];
            hc = hc > 0.f ? hc : 0.2f * hc;
            out[(size_t)(b * HID + d) * NPIX + pix] = (1.f - z) * hc + z * hpv;
        }
    }
}

// ---------------------------------------------------------------------------
extern "C" void kernel_launch(void* const* d_in, const int* in_sizes, int n_in,
                              void* d_out, int out_size, void* d_ws, size_t ws_size,
                              hipStream_t stream)
{
    const float* x      = (const float*)d_in[0];
    const float* hp     = (const float*)d_in[1];
    const float* w_in   = (const float*)d_in[2];
    const float* b_in   = (const float*)d_in[3];
    const float* w_proj = (const float*)d_in[4];
    const float* b_proj = (const float*)d_in[5];
    const float* w_sub  = (const float*)d_in[6];
    const float* b_sub  = (const float*)d_in[7];
    float* out = (float*)d_out;

    // ws layout (bytes). xcl aliases ccbuf: xcl is dead before conv_sub runs.
    char* ws = (char*)d_ws;
    __hip_bfloat16* icbuf   = (__hip_bfloat16*)ws;               // 100,663,296
    __hip_bfloat16* xcl     = (__hip_bfloat16*)(ws + 100663296); //  16,777,216 (alias)
    float*          ccbuf   = (float*)         (ws + 100663296); //  16,777,216 (alias)
    unsigned*       minmax  = (unsigned*)      (ws + 117440512); //         256
    float*          wsub_rp = (float*)         (ws + 117440768); //     153,600
    float*          bsum    = (float*)         (ws + 117594368); //       1,024
    __hip_bfloat16* win_frag= (__hip_bfloat16*)(ws + 117595392); //     110,592
    __hip_bfloat16* wp_frag = (__hip_bfloat16*)(ws + 117705984); //      98,304

    repack_kernel<<<dim3(559), dim3(256), 0, stream>>>(
        w_in, w_sub, w_proj, b_proj, wsub_rp, bsum, win_frag, wp_frag, minmax);
    transpose_x_kernel<<<dim3(HW_, B_), dim3(256), 0, stream>>>(x, xcl);
    conv_in_mfma<<<dim3(8, 16, B_), dim3(256), 0, stream>>>(
        xcl, win_frag, b_in, icbuf);
    conv_sub_kernel<<<dim3(8, 8, B_), dim3(256), 0, stream>>>(
        x, hp, wsub_rp, b_sub, ccbuf, minmax);
    warp_gru_kernel<<<dim3(2, HW_, B_), dim3(256), 0, stream>>>(
        hp, ccbuf, wp_frag, bsum, icbuf, minmax, out);
}

// Round 3
// 687.739 us; speedup vs baseline: 2.1741x; 1.3454x over previous
//
#include <hip/hip_runtime.h>
#include <hip/hip_bf16.h>
#include <math.h>

// Problem constants
#define B_    16
#define HID   64
#define CIN   32
#define OC1   192   // 3*HID
#define CCC   16    // 2*CONNECTION
#define HW_   128
#define NPIX  (HW_*HW_)

typedef short short8 __attribute__((ext_vector_type(8)));      // 8 bf16
typedef _Float16 half8 __attribute__((ext_vector_type(8)));    // 8 fp16
typedef float floatx4 __attribute__((ext_vector_type(4)));     // MFMA C/D

// ---- sortable-uint encoding for float atomicMin/Max ----
__device__ __forceinline__ unsigned fenc(float f) {
    unsigned b = __float_as_uint(f);
    return (b & 0x80000000u) ? ~b : (b | 0x80000000u);
}
__device__ __forceinline__ float fdec(unsigned u) {
    unsigned b = (u & 0x80000000u) ? (u ^ 0x80000000u) : ~u;
    return __uint_as_float(b);
}

// ---------------------------------------------------------------------------
// K0: repack weights + init minmax
//  wsub_f16[sk=s*3+kc][lane][j] fp16 : A-frags conv_sub. oc=lane&15,
//     icg = kc*32+(lane>>4)*8+j, s=ky*5+kx   (75*64*8)
//  bsum    [o] = sum_i b_proj[i][o]  : 192 fp32
//  win_frag[s][mt][lane][j] bf16     : A-frags conv_in  (9*12*64*8)
//  wp_frag [kt][mt][lane][j] bf16    : A-frags warp proj (8*12*64*8)
// ---------------------------------------------------------------------------
__global__ __launch_bounds__(256) void repack_kernel(
    const float* __restrict__ w_in, const float* __restrict__ w_sub,
    const float* __restrict__ w_proj, const float* __restrict__ b_proj,
    _Float16* __restrict__ wsub_f16, float* __restrict__ bsum,
    __hip_bfloat16* __restrict__ win_frag, __hip_bfloat16* __restrict__ wp_frag,
    unsigned* __restrict__ minmax)
{
    int idx = blockIdx.x * 256 + threadIdx.x;
    if (idx < 38400) {                       // wsub_f16 frags
        int sk = idx >> 9, r2 = idx & 511;
        int l = r2 >> 3, j = r2 & 7;
        int s = sk / 3, kc = sk - s * 3;
        int ky = s / 5, kx = s - ky * 5;
        int oc = l & 15;
        int icg = kc * 32 + (l >> 4) * 8 + j;
        wsub_f16[idx] = (_Float16)w_sub[oc * 2400 + icg * 25 + ky * 5 + kx];
    } else if (idx < 38400 + 192) {
        int o = idx - 38400;
        bsum[o] = b_proj[o] + b_proj[192 + o] + b_proj[384 + o] + b_proj[576 + o];
    } else if (idx < 38592 + 55296) {        // win_frag
        int j2 = idx - 38592;
        int s = j2 / 6144, r = j2 - s * 6144;
        int mt = r / 512, r2 = r - mt * 512;
        int l = r2 >> 3, j = r2 & 7;
        int oc = mt * 16 + (l & 15);
        int ic = (l >> 4) * 8 + j;
        win_frag[j2] = __float2bfloat16(w_in[oc * 288 + ic * 9 + s]);
    } else if (idx < 38592 + 55296 + 49152) { // wp_frag
        int j3 = idx - (38592 + 55296);
        int kt = j3 / 6144, r = j3 - kt * 6144;
        int mt = r / 512, r2 = r - mt * 512;
        int l = r2 >> 3, j = r2 & 7;
        int o = mt * 16 + (l & 15);
        int c_all = kt * 32 + (l >> 4) * 8 + j;
        int i = c_all >> 6, c = c_all & 63;
        wp_frag[j3] = __float2bfloat16(w_proj[(i * 192 + o) * 64 + c]);
    }
    if (idx == 0) { minmax[0] = 0xFFFFFFFFu; minmax[1] = 0u; }
}

// ---------------------------------------------------------------------------
// K0b: transpose x to channels-last bf16: xcl[b][y][x][ic]
// ---------------------------------------------------------------------------
__global__ __launch_bounds__(256) void transpose_x_kernel(
    const float* __restrict__ x, __hip_bfloat16* __restrict__ xcl)
{
    __shared__ float lds[32 * 129];
    int tid = threadIdx.x;
    int y = blockIdx.x, b = blockIdx.y;
    const float* xb = x + (size_t)b * CIN * NPIX + y * HW_;
#pragma unroll
    for (int it = 0; it < 16; ++it) {
        int idx = tid + it * 256;
        int ic = idx >> 7, xx = idx & 127;
        lds[ic * 129 + xx] = xb[(size_t)ic * NPIX + xx];
    }
    __syncthreads();
    __hip_bfloat16* o = xcl + (size_t)((b * HW_ + y) * HW_) * 32;
#pragma unroll
    for (int it = 0; it < 16; ++it) {
        int e = tid + it * 256;
        int ic = e & 31, xx = e >> 5;
        o[e] = __float2bfloat16(lds[ic * 129 + xx]);
    }
}

// ---------------------------------------------------------------------------
// K1: conv_in as MFMA implicit GEMM (unchanged from R2).
// ---------------------------------------------------------------------------
__global__ __launch_bounds__(256) void conv_in_mfma(
    const __hip_bfloat16* __restrict__ xcl,
    const __hip_bfloat16* __restrict__ win_frag,
    const float* __restrict__ b_in, __hip_bfloat16* __restrict__ icbuf)
{
    __shared__ __align__(16) __hip_bfloat16 xt[10 * 18 * 32];  // 11520 B
    int tid = threadIdx.x;
    int w = tid >> 6, l = tid & 63;
    int quad = l >> 4, ln = l & 15;
    int b = blockIdx.z;
    int y0 = blockIdx.y * 8, x0 = blockIdx.x * 16;

    for (int idx = tid; idx < 720; idx += 256) {
        int pos = idx >> 2, ch = idx & 3;
        int yy = pos / 18, xx = pos - yy * 18;
        int gy = y0 + yy - 1, gx = x0 + xx - 1;
        uint4 v = make_uint4(0, 0, 0, 0);
        if ((unsigned)gy < 128u && (unsigned)gx < 128u)
            v = ((const uint4*)(xcl + (size_t)((b * HW_ + gy) * HW_ + gx) * 32))[ch];
        ((uint4*)(xt + pos * 32))[ch] = v;
    }
    __syncthreads();

    floatx4 acc[3][8];
#pragma unroll
    for (int a = 0; a < 3; ++a) {
        int ocb = (3 * w + a) * 16 + quad * 4;
        floatx4 init;
        init[0] = b_in[ocb]; init[1] = b_in[ocb + 1];
        init[2] = b_in[ocb + 2]; init[3] = b_in[ocb + 3];
#pragma unroll
        for (int nt = 0; nt < 8; ++nt) acc[a][nt] = init;
    }

#pragma unroll
    for (int s = 0; s < 9; ++s) {
        int ky = s / 3, kx = s - ky * 3;
        short8 af[3];
#pragma unroll
        for (int a = 0; a < 3; ++a)
            af[a] = *(const short8*)(win_frag + (size_t)((s * 12 + (3 * w + a)) * 64 + l) * 8);
#pragma unroll
        for (int nt = 0; nt < 8; ++nt) {
            int pos = (nt + ky) * 18 + (ln + kx);
            short8 bf = *(const short8*)(xt + pos * 32 + quad * 8);
#pragma unroll
            for (int a = 0; a < 3; ++a)
                acc[a][nt] = __builtin_amdgcn_mfma_f32_16x16x32_bf16(af[a], bf, acc[a][nt], 0, 0, 0);
        }
    }

#pragma unroll
    for (int a = 0; a < 3; ++a) {
#pragma unroll
        for (int nt = 0; nt < 8; ++nt) {
#pragma unroll
            for (int r = 0; r < 4; ++r) {
                int oc = (3 * w + a) * 16 + quad * 4 + r;
                icbuf[(size_t)(b * OC1 + oc) * NPIX + (y0 + nt) * HW_ + x0 + ln] =
                    __float2bfloat16(acc[a][nt][r]);
            }
        }
    }
}

// ---------------------------------------------------------------------------
// K2: conv_sub as fp16 MFMA implicit GEMM + fused global min/max.
//   Block: 16x8 px tile. LDS tile [yy 0..11][xx 0..19][icg 0..95] fp16,
//   built by fused in-kernel transpose from planar fp32 x / h_prev.
//   C[16 oc][128 px]: one m-tile; wave w owns px-rows {2w, 2w+1}.
// ---------------------------------------------------------------------------
__global__ __launch_bounds__(256) void conv_sub_mfma(
    const float* __restrict__ x, const float* __restrict__ hp,
    const _Float16* __restrict__ wsub_f16, const float* __restrict__ b_sub,
    float* __restrict__ cc, unsigned* __restrict__ minmax)
{
    __shared__ __align__(16) _Float16 tile[12 * 20 * 96];  // 46080 B
    __shared__ float redmn[4], redmx[4];
    int tid = threadIdx.x;
    int b = blockIdx.z;
    int y0 = blockIdx.y * 8, x0 = blockIdx.x * 16;

    // stage + transpose: 48 ic-pairs x 12 yy x 20 xx, 45 items/thread
#pragma unroll 5
    for (int it = 0; it < 45; ++it) {
        int idx = tid + it * 256;
        int icp = idx / 240;
        int r = idx - icp * 240;
        int yy = r / 20, xx = r - (r / 20) * 20;
        int gy = y0 + yy - 2, gx = x0 + xx - 2;
        int icg = icp * 2;
        float v0 = 0.f, v1 = 0.f;
        if ((unsigned)gy < 128u && (unsigned)gx < 128u) {
            const float* s0 = (icg < 32)
                ? &x[((size_t)(b * CIN + icg) * HW_ + gy) * HW_ + gx]
                : &hp[((size_t)(b * HID + (icg - 32)) * HW_ + gy) * HW_ + gx];
            v0 = s0[0];
            v1 = s0[NPIX];     // next channel plane (pair never straddles x/hp)
        }
        union { _Float16 h[2]; unsigned u; } pk;
        pk.h[0] = (_Float16)v0; pk.h[1] = (_Float16)v1;
        *(unsigned*)&tile[(yy * 20 + xx) * 96 + icg] = pk.u;
    }
    __syncthreads();

    int w = tid >> 6, l = tid & 63;
    int quad = l >> 4, ln = l & 15;

    floatx4 init;
#pragma unroll
    for (int r = 0; r < 4; ++r) init[r] = b_sub[quad * 4 + r];
    floatx4 acc[2] = {init, init};

#pragma unroll 5
    for (int s = 0; s < 25; ++s) {
        int ky = s / 5, kx = s - (s / 5) * 5;
#pragma unroll
        for (int kc = 0; kc < 3; ++kc) {
            half8 af = *(const half8*)(wsub_f16 + (size_t)((s * 3 + kc) * 64 + l) * 8);
#pragma unroll
            for (int t = 0; t < 2; ++t) {
                int pos = (w * 2 + t + ky) * 20 + (ln + kx);
                half8 bf = *(const half8*)(tile + pos * 96 + kc * 32 + quad * 8);
                acc[t] = __builtin_amdgcn_mfma_f32_16x16x32_f16(af, bf, acc[t], 0, 0, 0);
            }
        }
    }

    // epilogue: store cc (fp32) + fused min/max
    float mn = 1e30f, mx = -1e30f;
#pragma unroll
    for (int t = 0; t < 2; ++t) {
        int yg = y0 + w * 2 + t;
#pragma unroll
        for (int r = 0; r < 4; ++r) {
            int oc = quad * 4 + r;
            float v = acc[t][r];
            cc[((size_t)(b * CCC + oc) * HW_ + yg) * HW_ + x0 + ln] = v;
            mn = fminf(mn, v); mx = fmaxf(mx, v);
        }
    }
#pragma unroll
    for (int m = 1; m < 64; m <<= 1) {
        mn = fminf(mn, __shfl_xor(mn, m, 64));
        mx = fmaxf(mx, __shfl_xor(mx, m, 64));
    }
    if (l == 0) { redmn[w] = mn; redmx[w] = mx; }
    __syncthreads();
    if (tid == 0) {
        float bmn = fminf(fminf(redmn[0], redmn[1]), fminf(redmn[2], redmn[3]));
        float bmx = fmaxf(fmaxf(redmx[0], redmx[1]), fmaxf(redmx[2], redmx[3]));
        atomicMin(&minmax[0], fenc(bmn));
        atomicMax(&minmax[1], fenc(bmx));
    }
}

// ---------------------------------------------------------------------------
// K3: fused grid_sample(4 warps) + MFMA projection + GRU gates (unchanged).
// ---------------------------------------------------------------------------
__global__ __launch_bounds__(256) void warp_gru_kernel(
    const float* __restrict__ hp, const float* __restrict__ cc,
    const __hip_bfloat16* __restrict__ wp_frag, const float* __restrict__ bsum,
    const __hip_bfloat16* __restrict__ icbuf, const unsigned* __restrict__ minmax,
    float* __restrict__ out)
{
    __shared__ __align__(16) __hip_bfloat16 warped[64 * 256];  // 32 KB
    int tid = threadIdx.x;
    int i = tid >> 6;
    int p = tid & 63;
    int b = blockIdx.z, y = blockIdx.y, xh = blockIdx.x;
    int xg = xh * 64 + p;

    float mn = fdec(minmax[0]), mx = fdec(minmax[1]);
    float scale = 2.0f / (mx - mn);

    int ccbase = ((b * CCC + 2 * i) * HW_ + y) * HW_ + xg;
    float gxn = (cc[ccbase] - mn) * scale - 1.0f;
    float gyn = (cc[ccbase + NPIX] - mn) * scale - 1.0f;
    float gx = (gxn + 1.0f) * 64.0f - 0.5f;
    float gy = (gyn + 1.0f) * 64.0f - 0.5f;
    float x0f = floorf(gx), y0f = floorf(gy);
    float wx1 = gx - x0f, wy1 = gy - y0f;
    float wx0 = 1.0f - wx1, wy0 = 1.0f - wy1;
    int ix0 = (int)x0f, iy0 = (int)y0f;
    int ix1 = ix0 + 1, iy1 = iy0 + 1;
    bool vx0 = (unsigned)ix0 < 128u, vx1 = (unsigned)ix1 < 128u;
    bool vy0 = (unsigned)iy0 < 128u, vy1 = (unsigned)iy1 < 128u;
    float a00 = (vx0 && vy0) ? wy0 * wx0 : 0.f;
    float a01 = (vx1 && vy0) ? wy0 * wx1 : 0.f;
    float a10 = (vx0 && vy1) ? wy1 * wx0 : 0.f;
    float a11 = (vx1 && vy1) ? wy1 * wx1 : 0.f;
    int cx0 = min(max(ix0, 0), 127), cx1 = min(max(ix1, 0), 127);
    int cy0 = min(max(iy0, 0), 127), cy1 = min(max(iy1, 0), 127);
    const float* hb = hp + (size_t)b * HID * NPIX;
    int o00 = cy0 * HW_ + cx0, o01 = cy0 * HW_ + cx1;
    int o10 = cy1 * HW_ + cx0, o11 = cy1 * HW_ + cx1;

#pragma unroll
    for (int t = 0; t < 8; ++t) {
        short8 pk;
#pragma unroll
        for (int e = 0; e < 8; ++e) {
            const float* hc = hb + (size_t)(t * 8 + e) * NPIX;
            float v = a00 * hc[o00] + a01 * hc[o01] + a10 * hc[o10] + a11 * hc[o11];
            __hip_bfloat16 bv = __float2bfloat16(v);
            pk[e] = *reinterpret_cast<short*>(&bv);
        }
        int cs = (i * 8 + t) ^ (p & 7);
        *(short8*)(warped + p * 256 + cs * 8) = pk;
    }
    __syncthreads();

    int w = i;
    int l = p;
    int quad = l >> 4, ln = l & 15;

    floatx4 acc[3][4];
#pragma unroll
    for (int t = 0; t < 3; ++t) {
        int ob = t * 64 + 16 * w + quad * 4;
        floatx4 init;
        init[0] = bsum[ob]; init[1] = bsum[ob + 1];
        init[2] = bsum[ob + 2]; init[3] = bsum[ob + 3];
#pragma unroll
        for (int nt = 0; nt < 4; ++nt) acc[t][nt] = init;
    }

#pragma unroll
    for (int kt = 0; kt < 8; ++kt) {
        short8 af[3];
#pragma unroll
        for (int t = 0; t < 3; ++t)
            af[t] = *(const short8*)(wp_frag + (size_t)((kt * 12 + (t * 4 + w)) * 64 + l) * 8);
#pragma unroll
        for (int nt = 0; nt < 4; ++nt) {
            int pxi = nt * 16 + ln;
            int cs = (kt * 4 + quad) ^ (pxi & 7);
            short8 bf = *(const short8*)(warped + pxi * 256 + cs * 8);
#pragma unroll
            for (int t = 0; t < 3; ++t)
                acc[t][nt] = __builtin_amdgcn_mfma_f32_16x16x32_bf16(af[t], bf, acc[t][nt], 0, 0, 0);
        }
    }

    const __hip_bfloat16* icb = icbuf + (size_t)b * OC1 * NPIX;
#pragma unroll
    for (int nt = 0; nt < 4; ++nt) {
#pragma unroll
        for (int r = 0; r < 4; ++r) {
            int d = 16 * w + quad * 4 + r;
            int pxi = nt * 16 + ln;
            int pix = y * HW_ + xh * 64 + pxi;
            float xz  = __bfloat162float(icb[(size_t)d * NPIX + pix]);
            float xr  = __bfloat162float(icb[(size_t)(64 + d) * NPIX + pix]);
            float xhv = __bfloat162float(icb[(size_t)(128 + d) * NPIX + pix]);
            float hpv = hb[(size_t)d * NPIX + pix];
            float z  = 1.0f / (1.0f + expf(-(xz + acc[0][nt][r])));
            float rg = 1.0f / (1.0f + expf(-(xr + acc[1][nt][r])));
            float hc = xhv + rg * acc[2][nt][r];
            hc = hc > 0.f ? hc : 0.2f * hc;
            out[(size_t)(b * HID + d) * NPIX + pix] = (1.f - z) * hc + z * hpv;
        }
    }
}

// ---------------------------------------------------------------------------
extern "C" void kernel_launch(void* const* d_in, const int* in_sizes, int n_in,
                              void* d_out, int out_size, void* d_ws, size_t ws_size,
                              hipStream_t stream)
{
    const float* x      = (const float*)d_in[0];
    const float* hp     = (const float*)d_in[1];
    const float* w_in   = (const float*)d_in[2];
    const float* b_in   = (const float*)d_in[3];
    const float* w_proj = (const float*)d_in[4];
    const float* b_proj = (const float*)d_in[5];
    const float* w_sub  = (const float*)d_in[6];
    const float* b_sub  = (const float*)d_in[7];
    float* out = (float*)d_out;

    // ws layout (bytes). xcl aliases ccbuf: xcl dead after conv_in,
    // cc written by conv_sub afterwards. Total ~117.8 MB (same as R2).
    char* ws = (char*)d_ws;
    __hip_bfloat16* icbuf   = (__hip_bfloat16*)ws;               // 100,663,296
    __hip_bfloat16* xcl     = (__hip_bfloat16*)(ws + 100663296); //  16,777,216 (alias)
    float*          ccbuf   = (float*)         (ws + 100663296); //  16,777,216 (alias)
    unsigned*       minmax  = (unsigned*)      (ws + 117440512); //         256
    _Float16*       wsub_f16= (_Float16*)      (ws + 117440768); //      76,800
    float*          bsum    = (float*)         (ws + 117517568); //       1,024
    __hip_bfloat16* win_frag= (__hip_bfloat16*)(ws + 117518592); //     110,592
    __hip_bfloat16* wp_frag = (__hip_bfloat16*)(ws + 117629184); //      98,304

    repack_kernel<<<dim3(559), dim3(256), 0, stream>>>(
        w_in, w_sub, w_proj, b_proj, wsub_f16, bsum, win_frag, wp_frag, minmax);
    transpose_x_kernel<<<dim3(HW_, B_), dim3(256), 0, stream>>>(x, xcl);
    conv_in_mfma<<<dim3(8, 16, B_), dim3(256), 0, stream>>>(
        xcl, win_frag, b_in, icbuf);
    conv_sub_mfma<<<dim3(8, 16, B_), dim3(256), 0, stream>>>(
        x, hp, wsub_f16, b_sub, ccbuf, minmax);
    warp_gru_kernel<<<dim3(2, HW_, B_), dim3(256), 0, stream>>>(
        hp, ccbuf, wp_frag, bsum, icbuf, minmax, out);
}

// Round 4
// 525.212 us; speedup vs baseline: 2.8469x; 1.3094x over previous
//
#include <hip/hip_runtime.h>
#include <hip/hip_bf16.h>
#include <math.h>

// Problem constants
#define B_    16
#define HID   64
#define CIN   32
#define OC1   192   // 3*HID
#define CCC   16    // 2*CONNECTION
#define HW_   128
#define NPIX  (HW_*HW_)

typedef short short8 __attribute__((ext_vector_type(8)));      // 8 bf16
typedef _Float16 half8 __attribute__((ext_vector_type(8)));    // 8 fp16
typedef float floatx4 __attribute__((ext_vector_type(4)));     // MFMA C/D

// ---- sortable-uint encoding for float atomicMin/Max ----
__device__ __forceinline__ unsigned fenc(float f) {
    unsigned b = __float_as_uint(f);
    return (b & 0x80000000u) ? ~b : (b | 0x80000000u);
}
__device__ __forceinline__ float fdec(unsigned u) {
    unsigned b = (u & 0x80000000u) ? (u ^ 0x80000000u) : ~u;
    return __uint_as_float(b);
}
__device__ __forceinline__ float b2f(short s) {
    return __uint_as_float(((unsigned)(unsigned short)s) << 16);
}

// ---------------------------------------------------------------------------
// K0: repack weights + init minmax (unchanged from R3)
// ---------------------------------------------------------------------------
__global__ __launch_bounds__(256) void repack_kernel(
    const float* __restrict__ w_in, const float* __restrict__ w_sub,
    const float* __restrict__ w_proj, const float* __restrict__ b_proj,
    _Float16* __restrict__ wsub_f16, float* __restrict__ bsum,
    __hip_bfloat16* __restrict__ win_frag, __hip_bfloat16* __restrict__ wp_frag,
    unsigned* __restrict__ minmax)
{
    int idx = blockIdx.x * 256 + threadIdx.x;
    if (idx < 38400) {                       // wsub_f16 frags
        int sk = idx >> 9, r2 = idx & 511;
        int l = r2 >> 3, j = r2 & 7;
        int s = sk / 3, kc = sk - s * 3;
        int ky = s / 5, kx = s - ky * 5;
        int oc = l & 15;
        int icg = kc * 32 + (l >> 4) * 8 + j;
        wsub_f16[idx] = (_Float16)w_sub[oc * 2400 + icg * 25 + ky * 5 + kx];
    } else if (idx < 38400 + 192) {
        int o = idx - 38400;
        bsum[o] = b_proj[o] + b_proj[192 + o] + b_proj[384 + o] + b_proj[576 + o];
    } else if (idx < 38592 + 55296) {        // win_frag
        int j2 = idx - 38592;
        int s = j2 / 6144, r = j2 - s * 6144;
        int mt = r / 512, r2 = r - mt * 512;
        int l = r2 >> 3, j = r2 & 7;
        int oc = mt * 16 + (l & 15);
        int ic = (l >> 4) * 8 + j;
        win_frag[j2] = __float2bfloat16(w_in[oc * 288 + ic * 9 + s]);
    } else if (idx < 38592 + 55296 + 49152) { // wp_frag
        int j3 = idx - (38592 + 55296);
        int kt = j3 / 6144, r = j3 - kt * 6144;
        int mt = r / 512, r2 = r - mt * 512;
        int l = r2 >> 3, j = r2 & 7;
        int o = mt * 16 + (l & 15);
        int c_all = kt * 32 + (l >> 4) * 8 + j;
        int i = c_all >> 6, c = c_all & 63;
        wp_frag[j3] = __float2bfloat16(w_proj[(i * 192 + o) * 64 + c]);
    }
    if (idx == 0) { minmax[0] = 0xFFFFFFFFu; minmax[1] = 0u; }
}

// ---------------------------------------------------------------------------
// K0b: transpose x to channels-last bf16: xcl[b][y][x][ic]  (unchanged)
// ---------------------------------------------------------------------------
__global__ __launch_bounds__(256) void transpose_x_kernel(
    const float* __restrict__ x, __hip_bfloat16* __restrict__ xcl)
{
    __shared__ float lds[32 * 129];
    int tid = threadIdx.x;
    int y = blockIdx.x, b = blockIdx.y;
    const float* xb = x + (size_t)b * CIN * NPIX + y * HW_;
#pragma unroll
    for (int it = 0; it < 16; ++it) {
        int idx = tid + it * 256;
        int ic = idx >> 7, xx = idx & 127;
        lds[ic * 129 + xx] = xb[(size_t)ic * NPIX + xx];
    }
    __syncthreads();
    __hip_bfloat16* o = xcl + (size_t)((b * HW_ + y) * HW_) * 32;
#pragma unroll
    for (int it = 0; it < 16; ++it) {
        int e = tid + it * 256;
        int ic = e & 31, xx = e >> 5;
        o[e] = __float2bfloat16(lds[ic * 129 + xx]);
    }
}

// ---------------------------------------------------------------------------
// K0c: transpose h_prev to channels-last bf16: hcl[b][y][x][c]  (NEW)
//   Pair-packed writes (4 B/lane) for coalescing; 2-way LDS aliasing is free.
// ---------------------------------------------------------------------------
__global__ __launch_bounds__(256) void transpose_h_kernel(
    const float* __restrict__ hp, __hip_bfloat16* __restrict__ hcl)
{
    __shared__ float lds[64 * 129];   // 33024 B
    int tid = threadIdx.x;
    int y = blockIdx.x, b = blockIdx.y;
    const float* hb = hp + (size_t)b * HID * NPIX + y * HW_;
#pragma unroll
    for (int it = 0; it < 32; ++it) {
        int idx = tid + it * 256;
        int c = idx >> 7, xx = idx & 127;
        lds[c * 129 + xx] = hb[(size_t)c * NPIX + xx];
    }
    __syncthreads();
    unsigned* o = (unsigned*)(hcl + (size_t)((b * HW_ + y) * HW_) * 64);
#pragma unroll
    for (int it = 0; it < 16; ++it) {
        int e2 = tid + it * 256;          // pair index: xx*32 + c2
        int c2 = e2 & 31, xx = e2 >> 5;
        __hip_bfloat16 b0 = __float2bfloat16(lds[(c2 * 2) * 129 + xx]);
        __hip_bfloat16 b1 = __float2bfloat16(lds[(c2 * 2 + 1) * 129 + xx]);
        union { __hip_bfloat16 h[2]; unsigned u; } pk;
        pk.h[0] = b0; pk.h[1] = b1;
        o[e2] = pk.u;
    }
}

// ---------------------------------------------------------------------------
// K1: conv_in as MFMA implicit GEMM (unchanged from R2).
// ---------------------------------------------------------------------------
__global__ __launch_bounds__(256) void conv_in_mfma(
    const __hip_bfloat16* __restrict__ xcl,
    const __hip_bfloat16* __restrict__ win_frag,
    const float* __restrict__ b_in, __hip_bfloat16* __restrict__ icbuf)
{
    __shared__ __align__(16) __hip_bfloat16 xt[10 * 18 * 32];  // 11520 B
    int tid = threadIdx.x;
    int w = tid >> 6, l = tid & 63;
    int quad = l >> 4, ln = l & 15;
    int b = blockIdx.z;
    int y0 = blockIdx.y * 8, x0 = blockIdx.x * 16;

    for (int idx = tid; idx < 720; idx += 256) {
        int pos = idx >> 2, ch = idx & 3;
        int yy = pos / 18, xx = pos - yy * 18;
        int gy = y0 + yy - 1, gx = x0 + xx - 1;
        uint4 v = make_uint4(0, 0, 0, 0);
        if ((unsigned)gy < 128u && (unsigned)gx < 128u)
            v = ((const uint4*)(xcl + (size_t)((b * HW_ + gy) * HW_ + gx) * 32))[ch];
        ((uint4*)(xt + pos * 32))[ch] = v;
    }
    __syncthreads();

    floatx4 acc[3][8];
#pragma unroll
    for (int a = 0; a < 3; ++a) {
        int ocb = (3 * w + a) * 16 + quad * 4;
        floatx4 init;
        init[0] = b_in[ocb]; init[1] = b_in[ocb + 1];
        init[2] = b_in[ocb + 2]; init[3] = b_in[ocb + 3];
#pragma unroll
        for (int nt = 0; nt < 8; ++nt) acc[a][nt] = init;
    }

#pragma unroll
    for (int s = 0; s < 9; ++s) {
        int ky = s / 3, kx = s - ky * 3;
        short8 af[3];
#pragma unroll
        for (int a = 0; a < 3; ++a)
            af[a] = *(const short8*)(win_frag + (size_t)((s * 12 + (3 * w + a)) * 64 + l) * 8);
#pragma unroll
        for (int nt = 0; nt < 8; ++nt) {
            int pos = (nt + ky) * 18 + (ln + kx);
            short8 bf = *(const short8*)(xt + pos * 32 + quad * 8);
#pragma unroll
            for (int a = 0; a < 3; ++a)
                acc[a][nt] = __builtin_amdgcn_mfma_f32_16x16x32_bf16(af[a], bf, acc[a][nt], 0, 0, 0);
        }
    }

#pragma unroll
    for (int a = 0; a < 3; ++a) {
#pragma unroll
        for (int nt = 0; nt < 8; ++nt) {
#pragma unroll
            for (int r = 0; r < 4; ++r) {
                int oc = (3 * w + a) * 16 + quad * 4 + r;
                icbuf[(size_t)(b * OC1 + oc) * NPIX + (y0 + nt) * HW_ + x0 + ln] =
                    __float2bfloat16(acc[a][nt][r]);
            }
        }
    }
}

// ---------------------------------------------------------------------------
// K2: conv_sub as fp16 MFMA implicit GEMM + fused global min/max (unchanged).
// ---------------------------------------------------------------------------
__global__ __launch_bounds__(256) void conv_sub_mfma(
    const float* __restrict__ x, const float* __restrict__ hp,
    const _Float16* __restrict__ wsub_f16, const float* __restrict__ b_sub,
    float* __restrict__ cc, unsigned* __restrict__ minmax)
{
    __shared__ __align__(16) _Float16 tile[12 * 20 * 96];  // 46080 B
    __shared__ float redmn[4], redmx[4];
    int tid = threadIdx.x;
    int b = blockIdx.z;
    int y0 = blockIdx.y * 8, x0 = blockIdx.x * 16;

#pragma unroll 5
    for (int it = 0; it < 45; ++it) {
        int idx = tid + it * 256;
        int icp = idx / 240;
        int r = idx - icp * 240;
        int yy = r / 20, xx = r - (r / 20) * 20;
        int gy = y0 + yy - 2, gx = x0 + xx - 2;
        int icg = icp * 2;
        float v0 = 0.f, v1 = 0.f;
        if ((unsigned)gy < 128u && (unsigned)gx < 128u) {
            const float* s0 = (icg < 32)
                ? &x[((size_t)(b * CIN + icg) * HW_ + gy) * HW_ + gx]
                : &hp[((size_t)(b * HID + (icg - 32)) * HW_ + gy) * HW_ + gx];
            v0 = s0[0];
            v1 = s0[NPIX];
        }
        union { _Float16 h[2]; unsigned u; } pk;
        pk.h[0] = (_Float16)v0; pk.h[1] = (_Float16)v1;
        *(unsigned*)&tile[(yy * 20 + xx) * 96 + icg] = pk.u;
    }
    __syncthreads();

    int w = tid >> 6, l = tid & 63;
    int quad = l >> 4, ln = l & 15;

    floatx4 init;
#pragma unroll
    for (int r = 0; r < 4; ++r) init[r] = b_sub[quad * 4 + r];
    floatx4 acc[2] = {init, init};

#pragma unroll 5
    for (int s = 0; s < 25; ++s) {
        int ky = s / 5, kx = s - (s / 5) * 5;
#pragma unroll
        for (int kc = 0; kc < 3; ++kc) {
            half8 af = *(const half8*)(wsub_f16 + (size_t)((s * 3 + kc) * 64 + l) * 8);
#pragma unroll
            for (int t = 0; t < 2; ++t) {
                int pos = (w * 2 + t + ky) * 20 + (ln + kx);
                half8 bf = *(const half8*)(tile + pos * 96 + kc * 32 + quad * 8);
                acc[t] = __builtin_amdgcn_mfma_f32_16x16x32_f16(af, bf, acc[t], 0, 0, 0);
            }
        }
    }

    float mn = 1e30f, mx = -1e30f;
#pragma unroll
    for (int t = 0; t < 2; ++t) {
        int yg = y0 + w * 2 + t;
#pragma unroll
        for (int r = 0; r < 4; ++r) {
            int oc = quad * 4 + r;
            float v = acc[t][r];
            cc[((size_t)(b * CCC + oc) * HW_ + yg) * HW_ + x0 + ln] = v;
            mn = fminf(mn, v); mx = fmaxf(mx, v);
        }
    }
#pragma unroll
    for (int m = 1; m < 64; m <<= 1) {
        mn = fminf(mn, __shfl_xor(mn, m, 64));
        mx = fmaxf(mx, __shfl_xor(mx, m, 64));
    }
    if (l == 0) { redmn[w] = mn; redmx[w] = mx; }
    __syncthreads();
    if (tid == 0) {
        float bmn = fminf(fminf(redmn[0], redmn[1]), fminf(redmn[2], redmn[3]));
        float bmx = fmaxf(fmaxf(redmx[0], redmx[1]), fmaxf(redmx[2], redmx[3]));
        atomicMin(&minmax[0], fenc(bmn));
        atomicMax(&minmax[1], fenc(bmx));
    }
}

// ---------------------------------------------------------------------------
// K3: fused grid_sample(4 warps) + MFMA projection + GRU gates.
//   Gather now reads channels-last bf16 hcl: 4 corners x 8 dwordx4 per lane
//   (was 256 scalar dword loads) — the R3 latency bottleneck.
// ---------------------------------------------------------------------------
__global__ __launch_bounds__(256) void warp_gru_kernel(
    const float* __restrict__ hp, const __hip_bfloat16* __restrict__ hcl,
    const float* __restrict__ cc,
    const __hip_bfloat16* __restrict__ wp_frag, const float* __restrict__ bsum,
    const __hip_bfloat16* __restrict__ icbuf, const unsigned* __restrict__ minmax,
    float* __restrict__ out)
{
    __shared__ __align__(16) __hip_bfloat16 warped[64 * 256];  // 32 KB
    int tid = threadIdx.x;
    int i = tid >> 6;
    int p = tid & 63;
    int b = blockIdx.z, y = blockIdx.y, xh = blockIdx.x;
    int xg = xh * 64 + p;

    float mn = fdec(minmax[0]), mx = fdec(minmax[1]);
    float scale = 2.0f / (mx - mn);

    int ccbase = ((b * CCC + 2 * i) * HW_ + y) * HW_ + xg;
    float gxn = (cc[ccbase] - mn) * scale - 1.0f;
    float gyn = (cc[ccbase + NPIX] - mn) * scale - 1.0f;
    float gx = (gxn + 1.0f) * 64.0f - 0.5f;
    float gy = (gyn + 1.0f) * 64.0f - 0.5f;
    float x0f = floorf(gx), y0f = floorf(gy);
    float wx1 = gx - x0f, wy1 = gy - y0f;
    float wx0 = 1.0f - wx1, wy0 = 1.0f - wy1;
    int ix0 = (int)x0f, iy0 = (int)y0f;
    int ix1 = ix0 + 1, iy1 = iy0 + 1;
    bool vx0 = (unsigned)ix0 < 128u, vx1 = (unsigned)ix1 < 128u;
    bool vy0 = (unsigned)iy0 < 128u, vy1 = (unsigned)iy1 < 128u;
    float a00 = (vx0 && vy0) ? wy0 * wx0 : 0.f;
    float a01 = (vx1 && vy0) ? wy0 * wx1 : 0.f;
    float a10 = (vx0 && vy1) ? wy1 * wx0 : 0.f;
    float a11 = (vx1 && vy1) ? wy1 * wx1 : 0.f;
    int cx0 = min(max(ix0, 0), 127), cx1 = min(max(ix1, 0), 127);
    int cy0 = min(max(iy0, 0), 127), cy1 = min(max(iy1, 0), 127);

    const __hip_bfloat16* hclb = hcl + (size_t)b * NPIX * 64;
    const short8* r00 = (const short8*)(hclb + (size_t)(cy0 * HW_ + cx0) * 64);
    const short8* r01 = (const short8*)(hclb + (size_t)(cy0 * HW_ + cx1) * 64);
    const short8* r10 = (const short8*)(hclb + (size_t)(cy1 * HW_ + cx0) * 64);
    const short8* r11 = (const short8*)(hclb + (size_t)(cy1 * HW_ + cx1) * 64);

#pragma unroll
    for (int t = 0; t < 8; ++t) {
        short8 c00 = r00[t], c01 = r01[t], c10 = r10[t], c11 = r11[t];
        short8 pk;
#pragma unroll
        for (int e = 0; e < 8; ++e) {
            float v = a00 * b2f(c00[e]) + a01 * b2f(c01[e])
                    + a10 * b2f(c10[e]) + a11 * b2f(c11[e]);
            __hip_bfloat16 bv = __float2bfloat16(v);
            pk[e] = *reinterpret_cast<short*>(&bv);
        }
        int cs = (i * 8 + t) ^ (p & 7);
        *(short8*)(warped + p * 256 + cs * 8) = pk;
    }
    __syncthreads();

    int w = i;
    int l = p;
    int quad = l >> 4, ln = l & 15;

    floatx4 acc[3][4];
#pragma unroll
    for (int t = 0; t < 3; ++t) {
        int ob = t * 64 + 16 * w + quad * 4;
        floatx4 init;
        init[0] = bsum[ob]; init[1] = bsum[ob + 1];
        init[2] = bsum[ob + 2]; init[3] = bsum[ob + 3];
#pragma unroll
        for (int nt = 0; nt < 4; ++nt) acc[t][nt] = init;
    }

#pragma unroll
    for (int kt = 0; kt < 8; ++kt) {
        short8 af[3];
#pragma unroll
        for (int t = 0; t < 3; ++t)
            af[t] = *(const short8*)(wp_frag + (size_t)((kt * 12 + (t * 4 + w)) * 64 + l) * 8);
#pragma unroll
        for (int nt = 0; nt < 4; ++nt) {
            int pxi = nt * 16 + ln;
            int cs = (kt * 4 + quad) ^ (pxi & 7);
            short8 bf = *(const short8*)(warped + pxi * 256 + cs * 8);
#pragma unroll
            for (int t = 0; t < 3; ++t)
                acc[t][nt] = __builtin_amdgcn_mfma_f32_16x16x32_bf16(af[t], bf, acc[t][nt], 0, 0, 0);
        }
    }

    const float* hb = hp + (size_t)b * HID * NPIX;
    const __hip_bfloat16* icb = icbuf + (size_t)b * OC1 * NPIX;
#pragma unroll
    for (int nt = 0; nt < 4; ++nt) {
#pragma unroll
        for (int r = 0; r < 4; ++r) {
            int d = 16 * w + quad * 4 + r;
            int pxi = nt * 16 + ln;
            int pix = y * HW_ + xh * 64 + pxi;
            float xz  = __bfloat162float(icb[(size_t)d * NPIX + pix]);
            float xr  = __bfloat162float(icb[(size_t)(64 + d) * NPIX + pix]);
            float xhv = __bfloat162float(icb[(size_t)(128 + d) * NPIX + pix]);
            float hpv = hb[(size_t)d * NPIX + pix];
            float z  = 1.0f / (1.0f + expf(-(xz + acc[0][nt][r])));
            float rg = 1.0f / (1.0f + expf(-(xr + acc[1][nt][r])));
            float hc = xhv + rg * acc[2][nt][r];
            hc = hc > 0.f ? hc : 0.2f * hc;
            out[(size_t)(b * HID + d) * NPIX + pix] = (1.f - z) * hc + z * hpv;
        }
    }
}

// ---------------------------------------------------------------------------
extern "C" void kernel_launch(void* const* d_in, const int* in_sizes, int n_in,
                              void* d_out, int out_size, void* d_ws, size_t ws_size,
                              hipStream_t stream)
{
    const float* x      = (const float*)d_in[0];
    const float* hp     = (const float*)d_in[1];
    const float* w_in   = (const float*)d_in[2];
    const float* b_in   = (const float*)d_in[3];
    const float* w_proj = (const float*)d_in[4];
    const float* b_proj = (const float*)d_in[5];
    const float* w_sub  = (const float*)d_in[6];
    const float* b_sub  = (const float*)d_in[7];
    float* out = (float*)d_out;

    // ws layout (bytes). xcl aliases ccbuf (xcl dead after conv_in).
    // hcl appended: total ~151.3 MB.
    char* ws = (char*)d_ws;
    __hip_bfloat16* icbuf   = (__hip_bfloat16*)ws;               // 100,663,296
    __hip_bfloat16* xcl     = (__hip_bfloat16*)(ws + 100663296); //  16,777,216 (alias)
    float*          ccbuf   = (float*)         (ws + 100663296); //  16,777,216 (alias)
    unsigned*       minmax  = (unsigned*)      (ws + 117440512); //         256
    _Float16*       wsub_f16= (_Float16*)      (ws + 117440768); //      76,800
    float*          bsum    = (float*)         (ws + 117517568); //       1,024
    __hip_bfloat16* win_frag= (__hip_bfloat16*)(ws + 117518592); //     110,592
    __hip_bfloat16* wp_frag = (__hip_bfloat16*)(ws + 117629184); //      98,304
    __hip_bfloat16* hcl     = (__hip_bfloat16*)(ws + 117727488); //  33,554,432

    repack_kernel<<<dim3(559), dim3(256), 0, stream>>>(
        w_in, w_sub, w_proj, b_proj, wsub_f16, bsum, win_frag, wp_frag, minmax);
    transpose_x_kernel<<<dim3(HW_, B_), dim3(256), 0, stream>>>(x, xcl);
    transpose_h_kernel<<<dim3(HW_, B_), dim3(256), 0, stream>>>(hp, hcl);
    conv_in_mfma<<<dim3(8, 16, B_), dim3(256), 0, stream>>>(
        xcl, win_frag, b_in, icbuf);
    conv_sub_mfma<<<dim3(8, 16, B_), dim3(256), 0, stream>>>(
        x, hp, wsub_f16, b_sub, ccbuf, minmax);
    warp_gru_kernel<<<dim3(2, HW_, B_), dim3(256), 0, stream>>>(
        hp, hcl, ccbuf, wp_frag, bsum, icbuf, minmax, out);
}

// Round 5
// 493.994 us; speedup vs baseline: 3.0268x; 1.0632x over previous
//
#include <hip/hip_runtime.h>
#include <hip/hip_bf16.h>
#include <math.h>

// Problem constants
#define B_    16
#define HID   64
#define CIN   32
#define OC1   192   // 3*HID
#define CCC   16    // 2*CONNECTION
#define HW_   128
#define NPIX  (HW_*HW_)

typedef short short8 __attribute__((ext_vector_type(8)));      // 8 bf16
typedef _Float16 half8 __attribute__((ext_vector_type(8)));    // 8 fp16
typedef float floatx4 __attribute__((ext_vector_type(4)));     // MFMA C/D

// ---- sortable-uint encoding for float atomicMin/Max ----
__device__ __forceinline__ unsigned fenc(float f) {
    unsigned b = __float_as_uint(f);
    return (b & 0x80000000u) ? ~b : (b | 0x80000000u);
}
__device__ __forceinline__ float fdec(unsigned u) {
    unsigned b = (u & 0x80000000u) ? (u ^ 0x80000000u) : ~u;
    return __uint_as_float(b);
}
__device__ __forceinline__ float b2f(short s) {
    return __uint_as_float(((unsigned)(unsigned short)s) << 16);
}

// ---------------------------------------------------------------------------
// K0: repack weights + init minmax
//  wsub_f16[sk=s*3+kc][lane][j] fp16 : A-frags conv_sub (75*64*8)
//  bsum    [o] = sum_i b_proj[i][o]  : 192 fp32
//  win_f16 [s][mt][lane][j] fp16     : A-frags conv_in  (9*12*64*8)
//  wp_frag [kt][mt][lane][j] bf16    : A-frags warp proj (8*12*64*8)
// ---------------------------------------------------------------------------
__global__ __launch_bounds__(256) void repack_kernel(
    const float* __restrict__ w_in, const float* __restrict__ w_sub,
    const float* __restrict__ w_proj, const float* __restrict__ b_proj,
    _Float16* __restrict__ wsub_f16, float* __restrict__ bsum,
    _Float16* __restrict__ win_f16, __hip_bfloat16* __restrict__ wp_frag,
    unsigned* __restrict__ minmax)
{
    int idx = blockIdx.x * 256 + threadIdx.x;
    if (idx < 38400) {                       // wsub_f16 frags
        int sk = idx >> 9, r2 = idx & 511;
        int l = r2 >> 3, j = r2 & 7;
        int s = sk / 3, kc = sk - s * 3;
        int ky = s / 5, kx = s - ky * 5;
        int oc = l & 15;
        int icg = kc * 32 + (l >> 4) * 8 + j;
        wsub_f16[idx] = (_Float16)w_sub[oc * 2400 + icg * 25 + ky * 5 + kx];
    } else if (idx < 38400 + 192) {
        int o = idx - 38400;
        bsum[o] = b_proj[o] + b_proj[192 + o] + b_proj[384 + o] + b_proj[576 + o];
    } else if (idx < 38592 + 55296) {        // win_f16
        int j2 = idx - 38592;
        int s = j2 / 6144, r = j2 - s * 6144;
        int mt = r / 512, r2 = r - mt * 512;
        int l = r2 >> 3, j = r2 & 7;
        int oc = mt * 16 + (l & 15);
        int ic = (l >> 4) * 8 + j;
        win_f16[j2] = (_Float16)w_in[oc * 288 + ic * 9 + s];
    } else if (idx < 38592 + 55296 + 49152) { // wp_frag
        int j3 = idx - (38592 + 55296);
        int kt = j3 / 6144, r = j3 - kt * 6144;
        int mt = r / 512, r2 = r - mt * 512;
        int l = r2 >> 3, j = r2 & 7;
        int o = mt * 16 + (l & 15);
        int c_all = kt * 32 + (l >> 4) * 8 + j;
        int i = c_all >> 6, c = c_all & 63;
        wp_frag[j3] = __float2bfloat16(w_proj[(i * 192 + o) * 64 + c]);
    }
    if (idx == 0) { minmax[0] = 0xFFFFFFFFu; minmax[1] = 0u; }
}

// ---------------------------------------------------------------------------
// K0c: transpose h_prev to channels-last bf16: hcl[b][y][x][c]
// ---------------------------------------------------------------------------
__global__ __launch_bounds__(256) void transpose_h_kernel(
    const float* __restrict__ hp, __hip_bfloat16* __restrict__ hcl)
{
    __shared__ float lds[64 * 129];   // 33024 B
    int tid = threadIdx.x;
    int y = blockIdx.x, b = blockIdx.y;
    const float* hb = hp + (size_t)b * HID * NPIX + y * HW_;
#pragma unroll
    for (int it = 0; it < 32; ++it) {
        int idx = tid + it * 256;
        int c = idx >> 7, xx = idx & 127;
        lds[c * 129 + xx] = hb[(size_t)c * NPIX + xx];
    }
    __syncthreads();
    unsigned* o = (unsigned*)(hcl + (size_t)((b * HW_ + y) * HW_) * 64);
#pragma unroll
    for (int it = 0; it < 16; ++it) {
        int e2 = tid + it * 256;          // pair index: xx*32 + c2
        int c2 = e2 & 31, xx = e2 >> 5;
        __hip_bfloat16 b0 = __float2bfloat16(lds[(c2 * 2) * 129 + xx]);
        __hip_bfloat16 b1 = __float2bfloat16(lds[(c2 * 2 + 1) * 129 + xx]);
        union { __hip_bfloat16 h[2]; unsigned u; } pk;
        pk.h[0] = b0; pk.h[1] = b1;
        o[e2] = pk.u;
    }
}

// ---------------------------------------------------------------------------
// K1: FUSED conv_in (3x3, 32->192) + conv_sub (5x5, 96->16), fp16 MFMA.
//   Block: 16x8 px tile, 4 waves. One LDS tile [yy 0..11][xx 0..19][ch 0..99]
//   fp16, ch-stride 100 (50 dwords == 18 mod 32 -> 16 lanes hit 16 distinct
//   banks; the old 32/96-ch strides were 8-way conflicted).
//   conv_sub: wave w owns px-rows {2w,2w+1}; 25*3*2 = 150 MFMAs.
//   conv_in : wave w owns m-tiles {3w..3w+2}, 8 n-rows; 9*3*8 = 216 MFMAs.
// ---------------------------------------------------------------------------
__global__ __launch_bounds__(256) void conv_fused_mfma(
    const float* __restrict__ x, const float* __restrict__ hp,
    const _Float16* __restrict__ wsub_f16, const float* __restrict__ b_sub,
    const _Float16* __restrict__ win_f16, const float* __restrict__ b_in,
    float* __restrict__ cc, unsigned* __restrict__ minmax,
    __hip_bfloat16* __restrict__ icbuf)
{
    __shared__ __align__(16) _Float16 tile[12 * 20 * 100];  // 48000 B
    __shared__ float redmn[4], redmx[4];
    int tid = threadIdx.x;
    int b = blockIdx.z;
    int y0 = blockIdx.y * 8, x0 = blockIdx.x * 16;

    // stage + transpose: 48 ch-pairs x 12 yy x 20 xx
#pragma unroll 5
    for (int it = 0; it < 45; ++it) {
        int idx = tid + it * 256;
        int icp = idx / 240;
        int r = idx - icp * 240;
        int yy = r / 20, xx = r - (r / 20) * 20;
        int gy = y0 + yy - 2, gx = x0 + xx - 2;
        int icg = icp * 2;
        float v0 = 0.f, v1 = 0.f;
        if ((unsigned)gy < 128u && (unsigned)gx < 128u) {
            const float* s0 = (icg < 32)
                ? &x[((size_t)(b * CIN + icg) * HW_ + gy) * HW_ + gx]
                : &hp[((size_t)(b * HID + (icg - 32)) * HW_ + gy) * HW_ + gx];
            v0 = s0[0];
            v1 = s0[NPIX];
        }
        union { _Float16 h[2]; unsigned u; } pk;
        pk.h[0] = (_Float16)v0; pk.h[1] = (_Float16)v1;
        *(unsigned*)&tile[(yy * 20 + xx) * 100 + icg] = pk.u;
    }
    __syncthreads();

    int w = tid >> 6, l = tid & 63;
    int quad = l >> 4, ln = l & 15;

    // ---- conv_sub part ----
    floatx4 sinit;
#pragma unroll
    for (int r = 0; r < 4; ++r) sinit[r] = b_sub[quad * 4 + r];
    floatx4 sacc[2] = {sinit, sinit};

#pragma unroll 5
    for (int s = 0; s < 25; ++s) {
        int ky = s / 5, kx = s - (s / 5) * 5;
#pragma unroll
        for (int kc = 0; kc < 3; ++kc) {
            half8 af = *(const half8*)(wsub_f16 + (size_t)((s * 3 + kc) * 64 + l) * 8);
#pragma unroll
            for (int t = 0; t < 2; ++t) {
                int pos = (w * 2 + t + ky) * 20 + (ln + kx);
                half8 bf = *(const half8*)(tile + pos * 100 + kc * 32 + quad * 8);
                sacc[t] = __builtin_amdgcn_mfma_f32_16x16x32_f16(af, bf, sacc[t], 0, 0, 0);
            }
        }
    }

    // conv_sub epilogue: store cc + fused min/max (store overlaps conv_in MFMAs)
    {
        float mn = 1e30f, mx = -1e30f;
#pragma unroll
        for (int t = 0; t < 2; ++t) {
            int yg = y0 + w * 2 + t;
#pragma unroll
            for (int r = 0; r < 4; ++r) {
                int oc = quad * 4 + r;
                float v = sacc[t][r];
                cc[((size_t)(b * CCC + oc) * HW_ + yg) * HW_ + x0 + ln] = v;
                mn = fminf(mn, v); mx = fmaxf(mx, v);
            }
        }
#pragma unroll
        for (int m = 1; m < 64; m <<= 1) {
            mn = fminf(mn, __shfl_xor(mn, m, 64));
            mx = fmaxf(mx, __shfl_xor(mx, m, 64));
        }
        if (l == 0) { redmn[w] = mn; redmx[w] = mx; }
    }

    // ---- conv_in part ----
    floatx4 iacc[3][8];
#pragma unroll
    for (int a = 0; a < 3; ++a) {
        int ocb = (3 * w + a) * 16 + quad * 4;
        floatx4 init;
        init[0] = b_in[ocb]; init[1] = b_in[ocb + 1];
        init[2] = b_in[ocb + 2]; init[3] = b_in[ocb + 3];
#pragma unroll
        for (int nt = 0; nt < 8; ++nt) iacc[a][nt] = init;
    }

#pragma unroll
    for (int s = 0; s < 9; ++s) {
        int ky = s / 3, kx = s - ky * 3;
        half8 af[3];
#pragma unroll
        for (int a = 0; a < 3; ++a)
            af[a] = *(const half8*)(win_f16 + (size_t)((s * 12 + (3 * w + a)) * 64 + l) * 8);
#pragma unroll
        for (int nt = 0; nt < 8; ++nt) {
            // conv_in pad=1: gy = y0+nt-1+ky -> yy = nt+1+ky-? tile yy = gy-(y0-2) = nt+ky+1
            int pos = (nt + ky + 1) * 20 + (ln + kx + 1);
            half8 bf = *(const half8*)(tile + pos * 100 + quad * 8);
#pragma unroll
            for (int a = 0; a < 3; ++a)
                iacc[a][nt] = __builtin_amdgcn_mfma_f32_16x16x32_f16(af[a], bf, iacc[a][nt], 0, 0, 0);
        }
    }

#pragma unroll
    for (int a = 0; a < 3; ++a) {
#pragma unroll
        for (int nt = 0; nt < 8; ++nt) {
#pragma unroll
            for (int r = 0; r < 4; ++r) {
                int oc = (3 * w + a) * 16 + quad * 4 + r;
                icbuf[(size_t)(b * OC1 + oc) * NPIX + (y0 + nt) * HW_ + x0 + ln] =
                    __float2bfloat16(iacc[a][nt][r]);
            }
        }
    }

    // finish min/max block reduction
    __syncthreads();
    if (tid == 0) {
        float bmn = fminf(fminf(redmn[0], redmn[1]), fminf(redmn[2], redmn[3]));
        float bmx = fmaxf(fmaxf(redmx[0], redmx[1]), fmaxf(redmx[2], redmx[3]));
        atomicMin(&minmax[0], fenc(bmn));
        atomicMax(&minmax[1], fenc(bmx));
    }
}

// ---------------------------------------------------------------------------
// K3: fused grid_sample(4 warps) + MFMA projection + GRU gates.
//   NEW: gate epilogue stages icbuf through LDS (reusing `warped`) with
//   fully-coalesced 128-B line loads, replacing 48 scattered 2-B loads/lane.
// ---------------------------------------------------------------------------
__global__ __launch_bounds__(256) void warp_gru_kernel(
    const float* __restrict__ hp, const __hip_bfloat16* __restrict__ hcl,
    const float* __restrict__ cc,
    const __hip_bfloat16* __restrict__ wp_frag, const float* __restrict__ bsum,
    const __hip_bfloat16* __restrict__ icbuf, const unsigned* __restrict__ minmax,
    float* __restrict__ out)
{
    __shared__ __align__(16) __hip_bfloat16 warped[64 * 256];  // 32 KB (reused)
    int tid = threadIdx.x;
    int i = tid >> 6;
    int p = tid & 63;
    int b = blockIdx.z, y = blockIdx.y, xh = blockIdx.x;
    int xg = xh * 64 + p;

    float mn = fdec(minmax[0]), mx = fdec(minmax[1]);
    float scale = 2.0f / (mx - mn);

    int ccbase = ((b * CCC + 2 * i) * HW_ + y) * HW_ + xg;
    float gxn = (cc[ccbase] - mn) * scale - 1.0f;
    float gyn = (cc[ccbase + NPIX] - mn) * scale - 1.0f;
    float gx = (gxn + 1.0f) * 64.0f - 0.5f;
    float gy = (gyn + 1.0f) * 64.0f - 0.5f;
    float x0f = floorf(gx), y0f = floorf(gy);
    float wx1 = gx - x0f, wy1 = gy - y0f;
    float wx0 = 1.0f - wx1, wy0 = 1.0f - wy1;
    int ix0 = (int)x0f, iy0 = (int)y0f;
    int ix1 = ix0 + 1, iy1 = iy0 + 1;
    bool vx0 = (unsigned)ix0 < 128u, vx1 = (unsigned)ix1 < 128u;
    bool vy0 = (unsigned)iy0 < 128u, vy1 = (unsigned)iy1 < 128u;
    float a00 = (vx0 && vy0) ? wy0 * wx0 : 0.f;
    float a01 = (vx1 && vy0) ? wy0 * wx1 : 0.f;
    float a10 = (vx0 && vy1) ? wy1 * wx0 : 0.f;
    float a11 = (vx1 && vy1) ? wy1 * wx1 : 0.f;
    int cx0 = min(max(ix0, 0), 127), cx1 = min(max(ix1, 0), 127);
    int cy0 = min(max(iy0, 0), 127), cy1 = min(max(iy1, 0), 127);

    const __hip_bfloat16* hclb = hcl + (size_t)b * NPIX * 64;
    const short8* r00 = (const short8*)(hclb + (size_t)(cy0 * HW_ + cx0) * 64);
    const short8* r01 = (const short8*)(hclb + (size_t)(cy0 * HW_ + cx1) * 64);
    const short8* r10 = (const short8*)(hclb + (size_t)(cy1 * HW_ + cx0) * 64);
    const short8* r11 = (const short8*)(hclb + (size_t)(cy1 * HW_ + cx1) * 64);

#pragma unroll
    for (int t = 0; t < 8; ++t) {
        short8 c00 = r00[t], c01 = r01[t], c10 = r10[t], c11 = r11[t];
        short8 pk;
#pragma unroll
        for (int e = 0; e < 8; ++e) {
            float v = a00 * b2f(c00[e]) + a01 * b2f(c01[e])
                    + a10 * b2f(c10[e]) + a11 * b2f(c11[e]);
            __hip_bfloat16 bv = __float2bfloat16(v);
            pk[e] = *reinterpret_cast<short*>(&bv);
        }
        int cs = (i * 8 + t) ^ (p & 7);
        *(short8*)(warped + p * 256 + cs * 8) = pk;
    }
    __syncthreads();

    int w = i;
    int l = p;
    int quad = l >> 4, ln = l & 15;

    floatx4 acc[3][4];
#pragma unroll
    for (int t = 0; t < 3; ++t) {
        int ob = t * 64 + 16 * w + quad * 4;
        floatx4 init;
        init[0] = bsum[ob]; init[1] = bsum[ob + 1];
        init[2] = bsum[ob + 2]; init[3] = bsum[ob + 3];
#pragma unroll
        for (int nt = 0; nt < 4; ++nt) acc[t][nt] = init;
    }

#pragma unroll
    for (int kt = 0; kt < 8; ++kt) {
        short8 af[3];
#pragma unroll
        for (int t = 0; t < 3; ++t)
            af[t] = *(const short8*)(wp_frag + (size_t)((kt * 12 + (t * 4 + w)) * 64 + l) * 8);
#pragma unroll
        for (int nt = 0; nt < 4; ++nt) {
            int pxi = nt * 16 + ln;
            int cs = (kt * 4 + quad) ^ (pxi & 7);
            short8 bf = *(const short8*)(warped + pxi * 256 + cs * 8);
#pragma unroll
            for (int t = 0; t < 3; ++t)
                acc[t][nt] = __builtin_amdgcn_mfma_f32_16x16x32_bf16(af[t], bf, acc[t][nt], 0, 0, 0);
        }
    }

    // ---- stage icbuf rows for these 64 px into LDS (coalesced 128-B lines) ----
    __syncthreads();   // done reading warped; reuse it
    unsigned short* icl = (unsigned short*)warped;   // [oc 0..191][px 0..63]
    {
        const unsigned short* icbase =
            (const unsigned short*)icbuf + (size_t)b * OC1 * NPIX + y * HW_ + xh * 64;
#pragma unroll
        for (int it = 0; it < 6; ++it) {
            int idx = tid + it * 256;          // 0..1535
            int oc = idx >> 3, seg = idx & 7;  // 8 x dwordx4 per 64-px row
            uint4 v = *(const uint4*)(icbase + (size_t)oc * NPIX + seg * 8);
            *(uint4*)(icl + oc * 64 + seg * 8) = v;
        }
    }
    __syncthreads();

    const float* hb = hp + (size_t)b * HID * NPIX;
#pragma unroll
    for (int nt = 0; nt < 4; ++nt) {
#pragma unroll
        for (int r = 0; r < 4; ++r) {
            int d = 16 * w + quad * 4 + r;
            int pxi = nt * 16 + ln;
            int pix = y * HW_ + xh * 64 + pxi;
            float xz  = b2f((short)icl[(size_t)d * 64 + pxi]);
            float xr  = b2f((short)icl[(size_t)(64 + d) * 64 + pxi]);
            float xhv = b2f((short)icl[(size_t)(128 + d) * 64 + pxi]);
            float hpv = hb[(size_t)d * NPIX + pix];
            float z  = 1.0f / (1.0f + expf(-(xz + acc[0][nt][r])));
            float rg = 1.0f / (1.0f + expf(-(xr + acc[1][nt][r])));
            float hc = xhv + rg * acc[2][nt][r];
            hc = hc > 0.f ? hc : 0.2f * hc;
            out[(size_t)(b * HID + d) * NPIX + pix] = (1.f - z) * hc + z * hpv;
        }
    }
}

// ---------------------------------------------------------------------------
extern "C" void kernel_launch(void* const* d_in, const int* in_sizes, int n_in,
                              void* d_out, int out_size, void* d_ws, size_t ws_size,
                              hipStream_t stream)
{
    const float* x      = (const float*)d_in[0];
    const float* hp     = (const float*)d_in[1];
    const float* w_in   = (const float*)d_in[2];
    const float* b_in   = (const float*)d_in[3];
    const float* w_proj = (const float*)d_in[4];
    const float* b_proj = (const float*)d_in[5];
    const float* w_sub  = (const float*)d_in[6];
    const float* b_sub  = (const float*)d_in[7];
    float* out = (float*)d_out;

    // ws layout (bytes), total ~151.3 MB (same as R4, proven).
    char* ws = (char*)d_ws;
    __hip_bfloat16* icbuf   = (__hip_bfloat16*)ws;               // 100,663,296
    float*          ccbuf   = (float*)         (ws + 100663296); //  16,777,216
    unsigned*       minmax  = (unsigned*)      (ws + 117440512); //         256
    _Float16*       wsub_f16= (_Float16*)      (ws + 117440768); //      76,800
    float*          bsum    = (float*)         (ws + 117517568); //       1,024
    _Float16*       win_f16 = (_Float16*)      (ws + 117518592); //     110,592
    __hip_bfloat16* wp_frag = (__hip_bfloat16*)(ws + 117629184); //      98,304
    __hip_bfloat16* hcl     = (__hip_bfloat16*)(ws + 117727488); //  33,554,432

    repack_kernel<<<dim3(559), dim3(256), 0, stream>>>(
        w_in, w_sub, w_proj, b_proj, wsub_f16, bsum, win_f16, wp_frag, minmax);
    transpose_h_kernel<<<dim3(HW_, B_), dim3(256), 0, stream>>>(hp, hcl);
    conv_fused_mfma<<<dim3(8, 16, B_), dim3(256), 0, stream>>>(
        x, hp, wsub_f16, b_sub, win_f16, b_in, ccbuf, minmax, icbuf);
    warp_gru_kernel<<<dim3(2, HW_, B_), dim3(256), 0, stream>>>(
        hp, hcl, ccbuf, wp_frag, bsum, icbuf, minmax, out);
}